// Round 7
// baseline (113.790 us; speedup 1.0000x reference)
//
#include <hip/hip_runtime.h>
#include <math.h>

typedef unsigned short ushort_t;
typedef __attribute__((ext_vector_type(8))) short bf16x8;
typedef __attribute__((ext_vector_type(4))) float f32x4;

#define B_SZ 4096
#define F_SZ 512
#define J_SZ 16
#define M_SZ 64
#define U_SZ 512
#define P_SZ 1024

__device__ __forceinline__ ushort_t f2bf(float f) {
    union { float f; unsigned int u; } v; v.f = f;
    unsigned int r = (v.u + 0x7FFFu + ((v.u >> 16) & 1u)) >> 16;
    return (ushort_t)r;
}

// async global->LDS, 16 bytes per lane (wave-uniform LDS base + lane*16)
__device__ __forceinline__ void gload_lds16(const void* g, void* l) {
    __builtin_amdgcn_global_load_lds(
        (const __attribute__((address_space(1))) unsigned int*)g,
        (__attribute__((address_space(3))) unsigned int*)l, 16, 0, 0);
}

// ---------------------------------------------------------------------------
// prep: block-role fused preprocessing (1472 blocks).
//   [0,1024):    h fp32->bf16 + h2            (4 rows/block)
//   [1024,1280): dom fp32->bf16 + d2          (4 rows/block)
//   [1280,1344): Gram partials Gpart[kc][j][64][64] (fp32, no atomics)
//   [1344,1472): W [p][u] -> Wt [u][p] bf16   (64x64 LDS transpose)
// ---------------------------------------------------------------------------
__global__ __launch_bounds__(256) void prep_kernel(const float* __restrict__ h,
                                                   const float* __restrict__ dom,
                                                   const float* __restrict__ W,
                                                   ushort_t* __restrict__ hbf,
                                                   ushort_t* __restrict__ dombf,
                                                   ushort_t* __restrict__ Wt,
                                                   float* __restrict__ h2,
                                                   float* __restrict__ d2,
                                                   float* __restrict__ Gpart) {
    const int bid = blockIdx.x;
    const int tid = threadIdx.x;

    if (bid < 1024) {                       // ---- cvt_h ----
        int b = bid * 4 + (tid >> 6);
        int lane = tid & 63;
        const float4* row = (const float4*)(h + (size_t)b * F_SZ);
        ushort4* orow = (ushort4*)(hbf + (size_t)b * F_SZ);
        float s = 0.f;
        for (int i = lane; i < F_SZ / 4; i += 64) {
            float4 v = row[i];
            s += v.x * v.x + v.y * v.y + v.z * v.z + v.w * v.w;
            ushort4 o; o.x = f2bf(v.x); o.y = f2bf(v.y); o.z = f2bf(v.z); o.w = f2bf(v.w);
            orow[i] = o;
        }
        for (int off = 32; off; off >>= 1) s += __shfl_down(s, off);
        if (lane == 0) h2[b] = s;
    } else if (bid < 1280) {                // ---- cvt_dom ----
        int p = (bid - 1024) * 4 + (tid >> 6);
        int lane = tid & 63;
        const float4* row = (const float4*)(dom + (size_t)p * F_SZ);
        ushort4* orow = (ushort4*)(dombf + (size_t)p * F_SZ);
        float s = 0.f;
        for (int i = lane; i < F_SZ / 4; i += 64) {
            float4 v = row[i];
            s += v.x * v.x + v.y * v.y + v.z * v.z + v.w * v.w;
            ushort4 o; o.x = f2bf(v.x); o.y = f2bf(v.y); o.z = f2bf(v.z); o.w = f2bf(v.w);
            orow[i] = o;
        }
        for (int off = 32; off; off >>= 1) s += __shfl_down(s, off);
        if (lane == 0) d2[p] = s;
    } else if (bid < 1344) {                // ---- Gram partial (j,kc) ----
        int idx = bid - 1280;
        int j = idx >> 2, kc = idx & 3;
        const float* base = dom + (size_t)j * M_SZ * F_SZ + kc * 128;
        __shared__ float As[32][68];
        int tx = tid & 15, ty = tid >> 4;
        float c[4][4] = {};
        for (int kk = 0; kk < 128; kk += 32) {
            for (int l = 0; l < 2; ++l) {
                int s = tid + l * 256;
                int r = s >> 3, c4 = (s & 7) << 2;
                float4 v = *(const float4*)&base[(size_t)r * F_SZ + kk + c4];
                As[c4 + 0][r] = v.x; As[c4 + 1][r] = v.y;
                As[c4 + 2][r] = v.z; As[c4 + 3][r] = v.w;
            }
            __syncthreads();
            for (int k = 0; k < 32; ++k) {
                float a[4], bv[4];
                for (int i = 0; i < 4; ++i) a[i] = As[k][ty * 4 + i];
                for (int i = 0; i < 4; ++i) bv[i] = As[k][tx * 4 + i];
                for (int i = 0; i < 4; ++i)
                    for (int l2 = 0; l2 < 4; ++l2) c[i][l2] += a[i] * bv[l2];
            }
            __syncthreads();
        }
        float* gout = Gpart + ((size_t)kc * 16 + j) * 4096;
        for (int i = 0; i < 4; ++i)
            for (int l2 = 0; l2 < 4; ++l2)
                gout[(ty * 4 + i) * 64 + tx * 4 + l2] = c[i][l2];
    } else {                                // ---- cvt_w (transpose) ----
        int idx = bid - 1344;
        int pt = (idx >> 3) * 64, ut = (idx & 7) * 64;
        __shared__ ushort_t T[64][72];
        for (int l = 0; l < 4; ++l) {
            int s = l * 256 + tid;
            int r = s >> 4, c4 = (s & 15) << 2;
            float4 v = *(const float4*)&W[(size_t)(pt + r) * U_SZ + ut + c4];
            T[c4 + 0][r] = f2bf(v.x); T[c4 + 1][r] = f2bf(v.y);
            T[c4 + 2][r] = f2bf(v.z); T[c4 + 3][r] = f2bf(v.w);
        }
        __syncthreads();
        for (int l = 0; l < 4; ++l) {
            int s = l * 256 + tid;
            int r2 = s >> 4, c4 = (s & 15) << 2;
            ushort4 o; o.x = T[r2][c4 + 0]; o.y = T[r2][c4 + 1];
            o.z = T[r2][c4 + 2]; o.w = T[r2][c4 + 3];
            *(ushort4*)&Wt[(size_t)(ut + r2) * P_SZ + pt + c4] = o;
        }
    }
}

// ---------------------------------------------------------------------------
// gemm1_mfma: cross = hbf . dombf^T, 128x128 tile, BK=64, XOR-swizzled LDS.
// 4 waves 2x2, wave-tile 64x64 -> 32 MFMA : 16 ds_read_b128 per k-iter
// (MFMA-bound). 256 blocks (1/CU). Epilogue: K=exp(-2*(h2+d2-2c)) -> sj
// (shfl), Kbf via LDS repack. Blocks x<2 also reduce kdd[j] from Gpart.
// ---------------------------------------------------------------------------
__global__ __launch_bounds__(256) void gemm1_mfma(const ushort_t* __restrict__ hbf,
                                                  const ushort_t* __restrict__ dombf,
                                                  const float* __restrict__ h2,
                                                  const float* __restrict__ d2,
                                                  const float* __restrict__ Gpart,
                                                  ushort_t* __restrict__ Kbf,
                                                  float* __restrict__ sj,
                                                  float* __restrict__ kdd) {
    __shared__ ushort_t smem[17408];         // 34 KB: As 128x64 + Bs 128x64 | LDSC 128x132
    short* As = (short*)smem;                // [128][64] swizzled
    short* Bs = (short*)(smem + 8192);       // [128][64] swizzled
    const int b0 = blockIdx.x * 128;
    const int p0 = blockIdx.y * 128;
    const int tid = threadIdx.x;
    const int wid = tid >> 6, lane = tid & 63;
    const int wm = wid >> 1, wn = wid & 1;
    const int lcol = lane & 15, quad = lane >> 4;

    f32x4 acc[4][4];
    for (int i = 0; i < 4; ++i)
        for (int n = 0; n < 4; ++n) acc[i][n] = (f32x4){0.f, 0.f, 0.f, 0.f};

    for (int kk = 0; kk < F_SZ; kk += 64) {
#pragma unroll
        for (int l = 0; l < 4; ++l) {        // A: 128 rows x 8 chunks
            int s = l * 256 + tid;
            int row = s >> 3, c = s & 7;
            int gc = c ^ (row & 7);
            gload_lds16(hbf + (size_t)(b0 + row) * F_SZ + kk + gc * 8, &As[s * 8]);
        }
#pragma unroll
        for (int l = 0; l < 4; ++l) {        // B: 128 rows x 8 chunks
            int s = l * 256 + tid;
            int row = s >> 3, c = s & 7;
            int gc = c ^ (row & 7);
            gload_lds16(dombf + (size_t)(p0 + row) * F_SZ + kk + gc * 8, &Bs[s * 8]);
        }
        __syncthreads();
        bf16x8 ar[4][2], br[4][2];
#pragma unroll
        for (int i = 0; i < 4; ++i) {
            int r = wm * 64 + i * 16 + lcol;
#pragma unroll
            for (int ks = 0; ks < 2; ++ks)
                ar[i][ks] = *(const bf16x8*)&As[r * 64 + ((ks * 4 + quad) ^ (r & 7)) * 8];
        }
#pragma unroll
        for (int n = 0; n < 4; ++n) {
            int r = wn * 64 + n * 16 + lcol;
#pragma unroll
            for (int ks = 0; ks < 2; ++ks)
                br[n][ks] = *(const bf16x8*)&Bs[r * 64 + ((ks * 4 + quad) ^ (r & 7)) * 8];
        }
#pragma unroll
        for (int ks = 0; ks < 2; ++ks)
#pragma unroll
            for (int i = 0; i < 4; ++i)
#pragma unroll
                for (int n = 0; n < 4; ++n)
                    acc[i][n] = __builtin_amdgcn_mfma_f32_16x16x32_bf16(ar[i][ks], br[n][ks], acc[i][n], 0, 0, 0);
        __syncthreads();
    }

    // ---- epilogue: exp, sj reduction (wave covers exactly one j), stash ----
    const int jg = (p0 >> 6) + wn;
    float d2v[4];
#pragma unroll
    for (int n = 0; n < 4; ++n) d2v[n] = d2[p0 + wn * 64 + n * 16 + lcol];

    unsigned int stash[4][4][2];
#pragma unroll
    for (int i = 0; i < 4; ++i) {
#pragma unroll
        for (int r = 0; r < 4; ++r) {
            int b = b0 + wm * 64 + i * 16 + quad * 4 + r;
            float h2v = h2[b];
            float rs = 0.f;
            ushort_t kv[4];
#pragma unroll
            for (int n = 0; n < 4; ++n) {
                float sq = h2v + d2v[n] - 2.f * acc[i][n][r];
                float kvf = __expf(-2.f * sq);
                kv[n] = f2bf(kvf);
                rs += kvf;
            }
            stash[i][r][0] = (unsigned int)kv[0] | ((unsigned int)kv[1] << 16);
            stash[i][r][1] = (unsigned int)kv[2] | ((unsigned int)kv[3] << 16);
            rs += __shfl_xor(rs, 1);
            rs += __shfl_xor(rs, 2);
            rs += __shfl_xor(rs, 4);
            rs += __shfl_xor(rs, 8);
            if (lcol == 0) sj[(size_t)b * J_SZ + jg] = rs * (1.f / M_SZ);
        }
    }

    // ---- repack: C-layout -> LDSC[128][132] -> coalesced 8B stores ----
    ushort_t* LDSC = smem;                   // 33.8 KB <= 34 KB
#pragma unroll
    for (int i = 0; i < 4; ++i) {
#pragma unroll
        for (int r = 0; r < 4; ++r) {
            int row = wm * 64 + i * 16 + quad * 4 + r;
#pragma unroll
            for (int n = 0; n < 4; ++n) {
                ushort_t v = (ushort_t)(stash[i][r][n >> 1] >> ((n & 1) * 16));
                LDSC[row * 132 + wn * 64 + n * 16 + lcol] = v;
            }
        }
    }
    __syncthreads();
#pragma unroll
    for (int l = 0; l < 16; ++l) {
        int u = l * 256 + tid;               // 4096 ushort4 units (128 rows x 32)
        int row = u >> 5, segc = (u & 31) * 4;
        ushort4 v = *(const ushort4*)&LDSC[row * 132 + segc];
        *(ushort4*)&Kbf[(size_t)(b0 + row) * P_SZ + p0 + segc] = v;
    }

    // ---- kdd duty: 16 designated blocks reduce kdd[j] from Gpart ----
    if (blockIdx.x < 2) {
        __syncthreads();                     // LDSC reads done; reuse smem
        float* sd2 = (float*)smem;           // 64 floats
        float* red = ((float*)smem) + 64;    // 256 floats
        int j = blockIdx.y * 2 + blockIdx.x; // y in [0,8) -> j in [0,16)
        if (tid < 64) sd2[tid] = d2[j * 64 + tid];
        __syncthreads();
        const float* g0 = Gpart + (size_t)(0 * 16 + j) * 4096;
        const float* g1 = Gpart + (size_t)(1 * 16 + j) * 4096;
        const float* g2 = Gpart + (size_t)(2 * 16 + j) * 4096;
        const float* g3 = Gpart + (size_t)(3 * 16 + j) * 4096;
        float a2 = 0.f;
        for (int s = tid; s < 4096; s += 256) {
            float G = g0[s] + g1[s] + g2[s] + g3[s];
            a2 += __expf(-2.f * (sd2[s >> 6] + sd2[s & 63] - 2.f * G));
        }
        red[tid] = a2;
        __syncthreads();
        for (int off = 128; off; off >>= 1) {
            if (tid < off) red[tid] += red[tid + off];
            __syncthreads();
        }
        if (tid == 0) kdd[j] = red[0] * (1.f / 4096.f);
    }
}

// ---------------------------------------------------------------------------
// gemm2_mfma: out = sum_j prob_j*(K_j . W_j + bias_j). 128x64 tile, BK=64 =
// one stage per j (16 MFMA : 12 ds_read per stage), prob folded per stage.
// XOR-swizzled LDS. 256 blocks. Softmax from sj+kdd in prologue.
// ---------------------------------------------------------------------------
__global__ __launch_bounds__(256) void gemm2_mfma(const ushort_t* __restrict__ Ks,
                                                  const ushort_t* __restrict__ Wt,
                                                  const float* __restrict__ sj,
                                                  const float* __restrict__ kdd,
                                                  const float* __restrict__ bias,
                                                  float* __restrict__ out) {
    __shared__ short As[128 * 64];           // 16 KB swizzled
    __shared__ short Bs[64 * 64];            // 8 KB swizzled
    __shared__ float probS[128 * 17];        // 8.5 KB
    __shared__ float biasS[16 * 64];         // 4 KB
    __shared__ float kddS[J_SZ];
    const int b0 = blockIdx.x * 128;
    const int u0 = blockIdx.y * 64;
    const int tid = threadIdx.x;
    const int wid = tid >> 6, lane = tid & 63;
    const int wm = wid >> 1, wn = wid & 1;
    const int lcol = lane & 15, quad = lane >> 4;

    if (tid < J_SZ) kddS[tid] = kdd[tid];
    {
        int rowj = tid >> 4, c4 = (tid & 15) << 2;
        *(float4*)&biasS[rowj * 64 + c4] = *(const float4*)&bias[(size_t)rowj * U_SZ + u0 + c4];
    }
    __syncthreads();
    if (tid < 128) {
        int b = b0 + tid;
        float lg[J_SZ], mx = -1e30f;
#pragma unroll
        for (int j = 0; j < J_SZ; ++j) {
            lg[j] = 2.f * sj[(size_t)b * J_SZ + j] - kddS[j] - 1.f;
            mx = fmaxf(mx, lg[j]);
        }
        float ssum = 0.f;
#pragma unroll
        for (int j = 0; j < J_SZ; ++j) { lg[j] = __expf(lg[j] - mx); ssum += lg[j]; }
        float inv = 1.f / ssum;
#pragma unroll
        for (int j = 0; j < J_SZ; ++j) probS[tid * 17 + j] = lg[j] * inv;
    }
    __syncthreads();

    f32x4 acc_tot[4][2];
    for (int i = 0; i < 4; ++i)
        for (int n = 0; n < 2; ++n) acc_tot[i][n] = (f32x4){0.f, 0.f, 0.f, 0.f};

    for (int jb = 0; jb < J_SZ; ++jb) {
        int kk = jb * 64;
#pragma unroll
        for (int l = 0; l < 4; ++l) {        // A: 128 rows x 8 chunks
            int s = l * 256 + tid;
            int row = s >> 3, c = s & 7;
            int gc = c ^ (row & 7);
            gload_lds16(Ks + (size_t)(b0 + row) * P_SZ + kk + gc * 8, &As[s * 8]);
        }
#pragma unroll
        for (int l = 0; l < 2; ++l) {        // B: 64 rows x 8 chunks
            int s = l * 256 + tid;
            int row = s >> 3, c = s & 7;
            int gc = c ^ (row & 7);
            gload_lds16(Wt + (size_t)(u0 + row) * P_SZ + kk + gc * 8, &Bs[s * 8]);
        }
        __syncthreads();
        bf16x8 ar[4][2], br[2][2];
#pragma unroll
        for (int i = 0; i < 4; ++i) {
            int r = wm * 64 + i * 16 + lcol;
#pragma unroll
            for (int ks = 0; ks < 2; ++ks)
                ar[i][ks] = *(const bf16x8*)&As[r * 64 + ((ks * 4 + quad) ^ (r & 7)) * 8];
        }
#pragma unroll
        for (int n = 0; n < 2; ++n) {
            int r = wn * 32 + n * 16 + lcol;
#pragma unroll
            for (int ks = 0; ks < 2; ++ks)
                br[n][ks] = *(const bf16x8*)&Bs[r * 64 + ((ks * 4 + quad) ^ (r & 7)) * 8];
        }
        f32x4 acc_cur[4][2];
#pragma unroll
        for (int i = 0; i < 4; ++i)
#pragma unroll
            for (int n = 0; n < 2; ++n) acc_cur[i][n] = (f32x4){0.f, 0.f, 0.f, 0.f};
#pragma unroll
        for (int ks = 0; ks < 2; ++ks)
#pragma unroll
            for (int i = 0; i < 4; ++i)
#pragma unroll
                for (int n = 0; n < 2; ++n)
                    acc_cur[i][n] = __builtin_amdgcn_mfma_f32_16x16x32_bf16(ar[i][ks], br[n][ks], acc_cur[i][n], 0, 0, 0);
        __syncthreads();
        // fold this domain's partial with its probability
#pragma unroll
        for (int i = 0; i < 4; ++i) {
#pragma unroll
            for (int r = 0; r < 4; ++r) {
                float pf = probS[(wm * 64 + i * 16 + quad * 4 + r) * 17 + jb];
#pragma unroll
                for (int n = 0; n < 2; ++n)
                    acc_tot[i][n][r] += pf * acc_cur[i][n][r];
            }
        }
    }

    // ---- epilogue: + sum_j prob*bias ----
    float bv[2][J_SZ];
#pragma unroll
    for (int n = 0; n < 2; ++n) {
        int col = wn * 32 + n * 16 + lcol;
#pragma unroll
        for (int j = 0; j < J_SZ; ++j) bv[n][j] = biasS[j * 64 + col];
    }
#pragma unroll
    for (int i = 0; i < 4; ++i) {
#pragma unroll
        for (int r = 0; r < 4; ++r) {
            int row = wm * 64 + i * 16 + quad * 4 + r;
            int b = b0 + row;
#pragma unroll
            for (int n = 0; n < 2; ++n) {
                float a = acc_tot[i][n][r];
#pragma unroll
                for (int j = 0; j < J_SZ; ++j) a += probS[row * 17 + j] * bv[n][j];
                out[(size_t)b * U_SZ + u0 + wn * 32 + n * 16 + lcol] = a;
            }
        }
    }
}

// ---------------------------------------------------------------------------
extern "C" void kernel_launch(void* const* d_in, const int* in_sizes, int n_in,
                              void* d_out, int out_size, void* d_ws, size_t ws_size,
                              hipStream_t stream) {
    const float* h    = (const float*)d_in[0];   // [B,F]
    const float* dom  = (const float*)d_in[1];   // [J,M,F]
    const float* W    = (const float*)d_in[2];   // [J,M,U]
    const float* bias = (const float*)d_in[3];   // [J,U]
    float* out = (float*)d_out;                  // [B,U]

    char* ws = (char*)d_ws;
    ushort_t* hbf   = (ushort_t*)ws;  ws += (size_t)B_SZ * F_SZ * 2;   // 4 MB
    ushort_t* dombf = (ushort_t*)ws;  ws += (size_t)P_SZ * F_SZ * 2;   // 1 MB
    ushort_t* Wt    = (ushort_t*)ws;  ws += (size_t)U_SZ * P_SZ * 2;   // 1 MB
    ushort_t* Kbf   = (ushort_t*)ws;  ws += (size_t)B_SZ * P_SZ * 2;   // 8 MB
    float* h2    = (float*)ws;  ws += B_SZ * 4;
    float* d2    = (float*)ws;  ws += P_SZ * 4;
    float* kdd   = (float*)ws;  ws += 64;
    float* sj    = (float*)ws;  ws += (size_t)B_SZ * J_SZ * 4;
    float* Gpart = (float*)ws;  ws += (size_t)4 * J_SZ * M_SZ * M_SZ * 4;  // 1 MB

    prep_kernel<<<1472, 256, 0, stream>>>(h, dom, W, hbf, dombf, Wt, h2, d2, Gpart);
    gemm1_mfma<<<dim3(B_SZ / 128, P_SZ / 128), 256, 0, stream>>>(hbf, dombf, h2, d2, Gpart, Kbf, sj, kdd);
    gemm2_mfma<<<dim3(B_SZ / 128, U_SZ / 64), 256, 0, stream>>>(Kbf, Wt, sj, kdd, bias, out);
}

// Round 8
// 103.644 us; speedup vs baseline: 1.0979x; 1.0979x over previous
//
#include <hip/hip_runtime.h>
#include <math.h>

typedef unsigned short ushort_t;
typedef __attribute__((ext_vector_type(8))) short bf16x8;
typedef __attribute__((ext_vector_type(4))) float f32x4;

#define B_SZ 4096
#define F_SZ 512
#define J_SZ 16
#define M_SZ 64
#define U_SZ 512
#define P_SZ 1024

__device__ __forceinline__ ushort_t f2bf(float f) {
    union { float f; unsigned int u; } v; v.f = f;
    unsigned int r = (v.u + 0x7FFFu + ((v.u >> 16) & 1u)) >> 16;
    return (ushort_t)r;
}

// async global->LDS, 16 bytes per lane (wave-uniform LDS base + lane*16)
__device__ __forceinline__ void gload_lds16(const void* g, void* l) {
    __builtin_amdgcn_global_load_lds(
        (const __attribute__((address_space(1))) unsigned int*)g,
        (__attribute__((address_space(3))) unsigned int*)l, 16, 0, 0);
}

// ---------------------------------------------------------------------------
// prep: block-role fused preprocessing (1472 blocks).  [unchanged from R6]
// ---------------------------------------------------------------------------
__global__ __launch_bounds__(256) void prep_kernel(const float* __restrict__ h,
                                                   const float* __restrict__ dom,
                                                   const float* __restrict__ W,
                                                   ushort_t* __restrict__ hbf,
                                                   ushort_t* __restrict__ dombf,
                                                   ushort_t* __restrict__ Wt,
                                                   float* __restrict__ h2,
                                                   float* __restrict__ d2,
                                                   float* __restrict__ Gpart) {
    const int bid = blockIdx.x;
    const int tid = threadIdx.x;

    if (bid < 1024) {                       // ---- cvt_h ----
        int b = bid * 4 + (tid >> 6);
        int lane = tid & 63;
        const float4* row = (const float4*)(h + (size_t)b * F_SZ);
        ushort4* orow = (ushort4*)(hbf + (size_t)b * F_SZ);
        float s = 0.f;
        for (int i = lane; i < F_SZ / 4; i += 64) {
            float4 v = row[i];
            s += v.x * v.x + v.y * v.y + v.z * v.z + v.w * v.w;
            ushort4 o; o.x = f2bf(v.x); o.y = f2bf(v.y); o.z = f2bf(v.z); o.w = f2bf(v.w);
            orow[i] = o;
        }
        for (int off = 32; off; off >>= 1) s += __shfl_down(s, off);
        if (lane == 0) h2[b] = s;
    } else if (bid < 1280) {                // ---- cvt_dom ----
        int p = (bid - 1024) * 4 + (tid >> 6);
        int lane = tid & 63;
        const float4* row = (const float4*)(dom + (size_t)p * F_SZ);
        ushort4* orow = (ushort4*)(dombf + (size_t)p * F_SZ);
        float s = 0.f;
        for (int i = lane; i < F_SZ / 4; i += 64) {
            float4 v = row[i];
            s += v.x * v.x + v.y * v.y + v.z * v.z + v.w * v.w;
            ushort4 o; o.x = f2bf(v.x); o.y = f2bf(v.y); o.z = f2bf(v.z); o.w = f2bf(v.w);
            orow[i] = o;
        }
        for (int off = 32; off; off >>= 1) s += __shfl_down(s, off);
        if (lane == 0) d2[p] = s;
    } else if (bid < 1344) {                // ---- Gram partial (j,kc) ----
        int idx = bid - 1280;
        int j = idx >> 2, kc = idx & 3;
        const float* base = dom + (size_t)j * M_SZ * F_SZ + kc * 128;
        __shared__ float As[32][68];
        int tx = tid & 15, ty = tid >> 4;
        float c[4][4] = {};
        for (int kk = 0; kk < 128; kk += 32) {
            for (int l = 0; l < 2; ++l) {
                int s = tid + l * 256;
                int r = s >> 3, c4 = (s & 7) << 2;
                float4 v = *(const float4*)&base[(size_t)r * F_SZ + kk + c4];
                As[c4 + 0][r] = v.x; As[c4 + 1][r] = v.y;
                As[c4 + 2][r] = v.z; As[c4 + 3][r] = v.w;
            }
            __syncthreads();
            for (int k = 0; k < 32; ++k) {
                float a[4], bv[4];
                for (int i = 0; i < 4; ++i) a[i] = As[k][ty * 4 + i];
                for (int i = 0; i < 4; ++i) bv[i] = As[k][tx * 4 + i];
                for (int i = 0; i < 4; ++i)
                    for (int l2 = 0; l2 < 4; ++l2) c[i][l2] += a[i] * bv[l2];
            }
            __syncthreads();
        }
        float* gout = Gpart + ((size_t)kc * 16 + j) * 4096;
        for (int i = 0; i < 4; ++i)
            for (int l2 = 0; l2 < 4; ++l2)
                gout[(ty * 4 + i) * 64 + tx * 4 + l2] = c[i][l2];
    } else {                                // ---- cvt_w (transpose) ----
        int idx = bid - 1344;
        int pt = (idx >> 3) * 64, ut = (idx & 7) * 64;
        __shared__ ushort_t T[64][72];
        for (int l = 0; l < 4; ++l) {
            int s = l * 256 + tid;
            int r = s >> 4, c4 = (s & 15) << 2;
            float4 v = *(const float4*)&W[(size_t)(pt + r) * U_SZ + ut + c4];
            T[c4 + 0][r] = f2bf(v.x); T[c4 + 1][r] = f2bf(v.y);
            T[c4 + 2][r] = f2bf(v.z); T[c4 + 3][r] = f2bf(v.w);
        }
        __syncthreads();
        for (int l = 0; l < 4; ++l) {
            int s = l * 256 + tid;
            int r2 = s >> 4, c4 = (s & 15) << 2;
            ushort4 o; o.x = T[r2][c4 + 0]; o.y = T[r2][c4 + 1];
            o.z = T[r2][c4 + 2]; o.w = T[r2][c4 + 3];
            *(ushort4*)&Wt[(size_t)(ut + r2) * P_SZ + pt + c4] = o;
        }
    }
}

// ---------------------------------------------------------------------------
// gemm1_mfma: cross = hbf . dombf^T, 64x128 tile, BK=128 (4 iters, 8
// barriers), XOR-swizzled LDS (gc = c ^ (row&15), 16 chunks/row -> 2-way
// aliasing = free). 512 blocks (2/CU). Epilogue: K=exp(-2*(h2+d2-2c)) -> sj
// (shfl), Kbf via LDS repack. Blocks x<2 also reduce kdd[j] from Gpart.
// ---------------------------------------------------------------------------
__global__ __launch_bounds__(256) void gemm1_mfma(const ushort_t* __restrict__ hbf,
                                                  const ushort_t* __restrict__ dombf,
                                                  const float* __restrict__ h2,
                                                  const float* __restrict__ d2,
                                                  const float* __restrict__ Gpart,
                                                  ushort_t* __restrict__ Kbf,
                                                  float* __restrict__ sj,
                                                  float* __restrict__ kdd) {
    __shared__ ushort_t smem[24576];         // 48 KB: As 64x128 (16K) + Bs 128x128 (32K)
    short* As = (short*)smem;                // [64][128] swizzled
    short* Bs = (short*)(smem + 8192);       // [128][128] swizzled
    const int b0 = blockIdx.x * 64;
    const int p0 = blockIdx.y * 128;
    const int tid = threadIdx.x;
    const int wid = tid >> 6, lane = tid & 63;
    const int wm = wid >> 1, wn = wid & 1;
    const int lcol = lane & 15, quad = lane >> 4;

    f32x4 acc[2][4];
    for (int i = 0; i < 2; ++i)
        for (int n = 0; n < 4; ++n) acc[i][n] = (f32x4){0.f, 0.f, 0.f, 0.f};

    for (int kk = 0; kk < F_SZ; kk += 128) {
#pragma unroll
        for (int l = 0; l < 4; ++l) {        // A: 64 rows x 16 chunks
            int s = l * 256 + tid;
            int row = s >> 4, c = s & 15;
            int gc = c ^ (row & 15);
            gload_lds16(hbf + (size_t)(b0 + row) * F_SZ + kk + gc * 8, &As[s * 8]);
        }
#pragma unroll
        for (int l = 0; l < 8; ++l) {        // B: 128 rows x 16 chunks
            int s = l * 256 + tid;
            int row = s >> 4, c = s & 15;
            int gc = c ^ (row & 15);
            gload_lds16(dombf + (size_t)(p0 + row) * F_SZ + kk + gc * 8, &Bs[s * 8]);
        }
        __syncthreads();
        bf16x8 ar[2][4], br[4][4];
#pragma unroll
        for (int i = 0; i < 2; ++i) {
            int r = wm * 32 + i * 16 + lcol;
#pragma unroll
            for (int ks = 0; ks < 4; ++ks)
                ar[i][ks] = *(const bf16x8*)&As[r * 128 + ((ks * 4 + quad) ^ (r & 15)) * 8];
        }
#pragma unroll
        for (int n = 0; n < 4; ++n) {
            int r = wn * 64 + n * 16 + lcol;
#pragma unroll
            for (int ks = 0; ks < 4; ++ks)
                br[n][ks] = *(const bf16x8*)&Bs[r * 128 + ((ks * 4 + quad) ^ (r & 15)) * 8];
        }
#pragma unroll
        for (int ks = 0; ks < 4; ++ks)
#pragma unroll
            for (int i = 0; i < 2; ++i)
#pragma unroll
                for (int n = 0; n < 4; ++n)
                    acc[i][n] = __builtin_amdgcn_mfma_f32_16x16x32_bf16(ar[i][ks], br[n][ks], acc[i][n], 0, 0, 0);
        __syncthreads();
    }

    // ---- epilogue: exp, sj reduction (wave covers exactly one j), stash ----
    const int jg = (p0 >> 6) + wn;
    float d2v[4];
#pragma unroll
    for (int n = 0; n < 4; ++n) d2v[n] = d2[p0 + wn * 64 + n * 16 + lcol];

    unsigned int stash[2][4][2];
#pragma unroll
    for (int i = 0; i < 2; ++i) {
#pragma unroll
        for (int r = 0; r < 4; ++r) {
            int b = b0 + wm * 32 + i * 16 + quad * 4 + r;
            float h2v = h2[b];
            float rs = 0.f;
            ushort_t kv[4];
#pragma unroll
            for (int n = 0; n < 4; ++n) {
                float sq = h2v + d2v[n] - 2.f * acc[i][n][r];
                float kvf = __expf(-2.f * sq);
                kv[n] = f2bf(kvf);
                rs += kvf;
            }
            stash[i][r][0] = (unsigned int)kv[0] | ((unsigned int)kv[1] << 16);
            stash[i][r][1] = (unsigned int)kv[2] | ((unsigned int)kv[3] << 16);
            rs += __shfl_xor(rs, 1);
            rs += __shfl_xor(rs, 2);
            rs += __shfl_xor(rs, 4);
            rs += __shfl_xor(rs, 8);
            if (lcol == 0) sj[(size_t)b * J_SZ + jg] = rs * (1.f / M_SZ);
        }
    }

    // ---- repack: C-layout -> LDSC[64][132] -> coalesced 8B stores ----
    ushort_t* LDSC = smem;                   // 16.9 KB <= 48 KB
#pragma unroll
    for (int i = 0; i < 2; ++i) {
#pragma unroll
        for (int r = 0; r < 4; ++r) {
            int row = wm * 32 + i * 16 + quad * 4 + r;
#pragma unroll
            for (int n = 0; n < 4; ++n) {
                ushort_t v = (ushort_t)(stash[i][r][n >> 1] >> ((n & 1) * 16));
                LDSC[row * 132 + wn * 64 + n * 16 + lcol] = v;
            }
        }
    }
    __syncthreads();
#pragma unroll
    for (int l = 0; l < 8; ++l) {
        int u = l * 256 + tid;               // 2048 ushort4 units
        int row = u >> 5, segc = (u & 31) * 4;
        ushort4 v = *(const ushort4*)&LDSC[row * 132 + segc];
        *(ushort4*)&Kbf[(size_t)(b0 + row) * P_SZ + p0 + segc] = v;
    }

    // ---- kdd duty: 16 designated blocks reduce kdd[j] from Gpart ----
    if (blockIdx.x < 2) {
        __syncthreads();                     // LDSC reads done; reuse smem
        float* sd2 = (float*)smem;           // 64 floats
        float* red = ((float*)smem) + 64;    // 256 floats
        int j = blockIdx.y * 2 + blockIdx.x;
        if (tid < 64) sd2[tid] = d2[j * 64 + tid];
        __syncthreads();
        const float* g0 = Gpart + (size_t)(0 * 16 + j) * 4096;
        const float* g1 = Gpart + (size_t)(1 * 16 + j) * 4096;
        const float* g2 = Gpart + (size_t)(2 * 16 + j) * 4096;
        const float* g3 = Gpart + (size_t)(3 * 16 + j) * 4096;
        float a2 = 0.f;
        for (int s = tid; s < 4096; s += 256) {
            float G = g0[s] + g1[s] + g2[s] + g3[s];
            a2 += __expf(-2.f * (sd2[s >> 6] + sd2[s & 63] - 2.f * G));
        }
        red[tid] = a2;
        __syncthreads();
        for (int off = 128; off; off >>= 1) {
            if (tid < off) red[tid] += red[tid + off];
            __syncthreads();
        }
        if (tid == 0) kdd[j] = red[0] * (1.f / 4096.f);
    }
}

// ---------------------------------------------------------------------------
// gemm2_mfma: out = sum_j prob_j*(K_j . W_j + bias_j). 64x64 tile, BK=128
// = TWO domains per stage (8 stages, 16 barriers), prob folded per domain.
// XOR-swizzled LDS (16 chunks/row). 512 blocks (2/CU, ~40 KB LDS).
// ---------------------------------------------------------------------------
__global__ __launch_bounds__(256) void gemm2_mfma(const ushort_t* __restrict__ Ks,
                                                  const ushort_t* __restrict__ Wt,
                                                  const float* __restrict__ sj,
                                                  const float* __restrict__ kdd,
                                                  const float* __restrict__ bias,
                                                  float* __restrict__ out) {
    __shared__ short As[64 * 128];           // 16 KB swizzled
    __shared__ short Bs[64 * 128];           // 16 KB swizzled
    __shared__ float probS[64 * 17];         // 4.25 KB
    __shared__ float biasS[16 * 64];         // 4 KB
    __shared__ float kddS[J_SZ];
    const int b0 = blockIdx.x * 64;
    const int u0 = blockIdx.y * 64;
    const int tid = threadIdx.x;
    const int wid = tid >> 6, lane = tid & 63;
    const int wm = wid >> 1, wn = wid & 1;
    const int lcol = lane & 15, quad = lane >> 4;

    if (tid < J_SZ) kddS[tid] = kdd[tid];
    {
        int rowj = tid >> 4, c4 = (tid & 15) << 2;
        *(float4*)&biasS[rowj * 64 + c4] = *(const float4*)&bias[(size_t)rowj * U_SZ + u0 + c4];
    }
    __syncthreads();
    if (tid < 64) {
        int b = b0 + tid;
        float lg[J_SZ], mx = -1e30f;
#pragma unroll
        for (int j = 0; j < J_SZ; ++j) {
            lg[j] = 2.f * sj[(size_t)b * J_SZ + j] - kddS[j] - 1.f;
            mx = fmaxf(mx, lg[j]);
        }
        float ssum = 0.f;
#pragma unroll
        for (int j = 0; j < J_SZ; ++j) { lg[j] = __expf(lg[j] - mx); ssum += lg[j]; }
        float inv = 1.f / ssum;
#pragma unroll
        for (int j = 0; j < J_SZ; ++j) probS[tid * 17 + j] = lg[j] * inv;
    }
    __syncthreads();

    f32x4 acc_tot[2][2];
    for (int i = 0; i < 2; ++i)
        for (int n = 0; n < 2; ++n) acc_tot[i][n] = (f32x4){0.f, 0.f, 0.f, 0.f};

    for (int jb = 0; jb < 8; ++jb) {
        int kk = jb * 128;                   // covers domains 2*jb, 2*jb+1
#pragma unroll
        for (int l = 0; l < 4; ++l) {        // A & B: 64 rows x 16 chunks each
            int s = l * 256 + tid;
            int row = s >> 4, c = s & 15;
            int gc = c ^ (row & 15);
            gload_lds16(Ks + (size_t)(b0 + row) * P_SZ + kk + gc * 8, &As[s * 8]);
            gload_lds16(Wt + (size_t)(u0 + row) * P_SZ + kk + gc * 8, &Bs[s * 8]);
        }
        __syncthreads();
        bf16x8 ar[2][4], br[2][4];
#pragma unroll
        for (int i = 0; i < 2; ++i) {
            int r = wm * 32 + i * 16 + lcol;
#pragma unroll
            for (int ks = 0; ks < 4; ++ks)
                ar[i][ks] = *(const bf16x8*)&As[r * 128 + ((ks * 4 + quad) ^ (r & 15)) * 8];
        }
#pragma unroll
        for (int n = 0; n < 2; ++n) {
            int r = wn * 32 + n * 16 + lcol;
#pragma unroll
            for (int ks = 0; ks < 4; ++ks)
                br[n][ks] = *(const bf16x8*)&Bs[r * 128 + ((ks * 4 + quad) ^ (r & 15)) * 8];
        }
        // domain 0 of this stage: ks 0,1 ; domain 1: ks 2,3
        f32x4 ac0[2][2], ac1[2][2];
#pragma unroll
        for (int i = 0; i < 2; ++i)
#pragma unroll
            for (int n = 0; n < 2; ++n) {
                ac0[i][n] = (f32x4){0.f, 0.f, 0.f, 0.f};
                ac1[i][n] = (f32x4){0.f, 0.f, 0.f, 0.f};
            }
#pragma unroll
        for (int ks = 0; ks < 2; ++ks)
#pragma unroll
            for (int i = 0; i < 2; ++i)
#pragma unroll
                for (int n = 0; n < 2; ++n)
                    ac0[i][n] = __builtin_amdgcn_mfma_f32_16x16x32_bf16(ar[i][ks], br[n][ks], ac0[i][n], 0, 0, 0);
#pragma unroll
        for (int ks = 2; ks < 4; ++ks)
#pragma unroll
            for (int i = 0; i < 2; ++i)
#pragma unroll
                for (int n = 0; n < 2; ++n)
                    ac1[i][n] = __builtin_amdgcn_mfma_f32_16x16x32_bf16(ar[i][ks], br[n][ks], ac1[i][n], 0, 0, 0);
        __syncthreads();
        // fold both domains' partials with their probabilities
#pragma unroll
        for (int i = 0; i < 2; ++i) {
#pragma unroll
            for (int r = 0; r < 4; ++r) {
                int row = wm * 32 + i * 16 + quad * 4 + r;
                float pf0 = probS[row * 17 + 2 * jb];
                float pf1 = probS[row * 17 + 2 * jb + 1];
#pragma unroll
                for (int n = 0; n < 2; ++n)
                    acc_tot[i][n][r] += pf0 * ac0[i][n][r] + pf1 * ac1[i][n][r];
            }
        }
    }

    // ---- epilogue: + sum_j prob*bias ----
    float bv[2][J_SZ];
#pragma unroll
    for (int n = 0; n < 2; ++n) {
        int col = wn * 32 + n * 16 + lcol;
#pragma unroll
        for (int j = 0; j < J_SZ; ++j) bv[n][j] = biasS[j * 64 + col];
    }
#pragma unroll
    for (int i = 0; i < 2; ++i) {
#pragma unroll
        for (int r = 0; r < 4; ++r) {
            int row = wm * 32 + i * 16 + quad * 4 + r;
            int b = b0 + row;
#pragma unroll
            for (int n = 0; n < 2; ++n) {
                float a = acc_tot[i][n][r];
#pragma unroll
                for (int j = 0; j < J_SZ; ++j) a += probS[row * 17 + j] * bv[n][j];
                out[(size_t)b * U_SZ + u0 + wn * 32 + n * 16 + lcol] = a;
            }
        }
    }
}

// ---------------------------------------------------------------------------
extern "C" void kernel_launch(void* const* d_in, const int* in_sizes, int n_in,
                              void* d_out, int out_size, void* d_ws, size_t ws_size,
                              hipStream_t stream) {
    const float* h    = (const float*)d_in[0];   // [B,F]
    const float* dom  = (const float*)d_in[1];   // [J,M,F]
    const float* W    = (const float*)d_in[2];   // [J,M,U]
    const float* bias = (const float*)d_in[3];   // [J,U]
    float* out = (float*)d_out;                  // [B,U]

    char* ws = (char*)d_ws;
    ushort_t* hbf   = (ushort_t*)ws;  ws += (size_t)B_SZ * F_SZ * 2;   // 4 MB
    ushort_t* dombf = (ushort_t*)ws;  ws += (size_t)P_SZ * F_SZ * 2;   // 1 MB
    ushort_t* Wt    = (ushort_t*)ws;  ws += (size_t)U_SZ * P_SZ * 2;   // 1 MB
    ushort_t* Kbf   = (ushort_t*)ws;  ws += (size_t)B_SZ * P_SZ * 2;   // 8 MB
    float* h2    = (float*)ws;  ws += B_SZ * 4;
    float* d2    = (float*)ws;  ws += P_SZ * 4;
    float* kdd   = (float*)ws;  ws += 64;
    float* sj    = (float*)ws;  ws += (size_t)B_SZ * J_SZ * 4;
    float* Gpart = (float*)ws;  ws += (size_t)4 * J_SZ * M_SZ * M_SZ * 4;  // 1 MB

    prep_kernel<<<1472, 256, 0, stream>>>(h, dom, W, hbf, dombf, Wt, h2, d2, Gpart);
    gemm1_mfma<<<dim3(B_SZ / 64, P_SZ / 128), 256, 0, stream>>>(hbf, dombf, h2, d2, Gpart, Kbf, sj, kdd);
    gemm2_mfma<<<dim3(B_SZ / 64, U_SZ / 64), 256, 0, stream>>>(Kbf, Wt, sj, kdd, bias, out);
}

// Round 9
// 95.161 us; speedup vs baseline: 1.1958x; 1.0891x over previous
//
#include <hip/hip_runtime.h>
#include <math.h>

typedef unsigned short ushort_t;
typedef __attribute__((ext_vector_type(8))) short bf16x8;
typedef __attribute__((ext_vector_type(4))) float f32x4;

#define B_SZ 4096
#define F_SZ 512
#define J_SZ 16
#define M_SZ 64
#define U_SZ 512
#define P_SZ 1024

__device__ __forceinline__ ushort_t f2bf(float f) {
    union { float f; unsigned int u; } v; v.f = f;
    unsigned int r = (v.u + 0x7FFFu + ((v.u >> 16) & 1u)) >> 16;
    return (ushort_t)r;
}

// async global->LDS, 16 bytes per lane (wave-uniform LDS base + lane*16)
__device__ __forceinline__ void gload_lds16(const void* g, void* l) {
    __builtin_amdgcn_global_load_lds(
        (const __attribute__((address_space(1))) unsigned int*)g,
        (__attribute__((address_space(3))) unsigned int*)l, 16, 0, 0);
}

// ---------------------------------------------------------------------------
// prep: block-role fused preprocessing (1408 blocks) — conversions only.
//   [0,1024):    h fp32->bf16 + h2            (4 rows/block)
//   [1024,1280): dom fp32->bf16 + d2          (4 rows/block)
//   [1280,1408): W [p][u] -> Wt [u][p] bf16   (64x64 LDS transpose)
// ---------------------------------------------------------------------------
__global__ __launch_bounds__(256) void prep_kernel(const float* __restrict__ h,
                                                   const float* __restrict__ dom,
                                                   const float* __restrict__ W,
                                                   ushort_t* __restrict__ hbf,
                                                   ushort_t* __restrict__ dombf,
                                                   ushort_t* __restrict__ Wt,
                                                   float* __restrict__ h2,
                                                   float* __restrict__ d2) {
    const int bid = blockIdx.x;
    const int tid = threadIdx.x;

    if (bid < 1024) {                       // ---- cvt_h ----
        int b = bid * 4 + (tid >> 6);
        int lane = tid & 63;
        const float4* row = (const float4*)(h + (size_t)b * F_SZ);
        ushort4* orow = (ushort4*)(hbf + (size_t)b * F_SZ);
        float s = 0.f;
        for (int i = lane; i < F_SZ / 4; i += 64) {
            float4 v = row[i];
            s += v.x * v.x + v.y * v.y + v.z * v.z + v.w * v.w;
            ushort4 o; o.x = f2bf(v.x); o.y = f2bf(v.y); o.z = f2bf(v.z); o.w = f2bf(v.w);
            orow[i] = o;
        }
        for (int off = 32; off; off >>= 1) s += __shfl_down(s, off);
        if (lane == 0) h2[b] = s;
    } else if (bid < 1280) {                // ---- cvt_dom ----
        int p = (bid - 1024) * 4 + (tid >> 6);
        int lane = tid & 63;
        const float4* row = (const float4*)(dom + (size_t)p * F_SZ);
        ushort4* orow = (ushort4*)(dombf + (size_t)p * F_SZ);
        float s = 0.f;
        for (int i = lane; i < F_SZ / 4; i += 64) {
            float4 v = row[i];
            s += v.x * v.x + v.y * v.y + v.z * v.z + v.w * v.w;
            ushort4 o; o.x = f2bf(v.x); o.y = f2bf(v.y); o.z = f2bf(v.z); o.w = f2bf(v.w);
            orow[i] = o;
        }
        for (int off = 32; off; off >>= 1) s += __shfl_down(s, off);
        if (lane == 0) d2[p] = s;
    } else {                                // ---- cvt_w (transpose) ----
        int idx = bid - 1280;
        int pt = (idx >> 3) * 64, ut = (idx & 7) * 64;
        __shared__ ushort_t T[64][72];
        for (int l = 0; l < 4; ++l) {
            int s = l * 256 + tid;
            int r = s >> 4, c4 = (s & 15) << 2;
            float4 v = *(const float4*)&W[(size_t)(pt + r) * U_SZ + ut + c4];
            T[c4 + 0][r] = f2bf(v.x); T[c4 + 1][r] = f2bf(v.y);
            T[c4 + 2][r] = f2bf(v.z); T[c4 + 3][r] = f2bf(v.w);
        }
        __syncthreads();
        for (int l = 0; l < 4; ++l) {
            int s = l * 256 + tid;
            int r2 = s >> 4, c4 = (s & 15) << 2;
            ushort4 o; o.x = T[r2][c4 + 0]; o.y = T[r2][c4 + 1];
            o.z = T[r2][c4 + 2]; o.w = T[r2][c4 + 3];
            *(ushort4*)&Wt[(size_t)(ut + r2) * P_SZ + pt + c4] = o;
        }
    }
}

// ---------------------------------------------------------------------------
// gemm1_mfma: 64x128 tile, BK=128 (4 iters), XOR-swizzled LDS. Grid (66, 8):
//   x in {0,1}: Gram blocks (dispatched FIRST): A = dombf rows of j=y*2+x;
//               epilogue reduces kdd[j] = mean exp(-2*(d2m+d2n-2*G)).
//   x >= 2:     normal: A = hbf rows (x-2)*64; K=exp(-2*(h2+d2-2c)) -> sj,
//               Kbf via LDS repack.
// 528 blocks (~2/CU).
// ---------------------------------------------------------------------------
__global__ __launch_bounds__(256) void gemm1_mfma(const ushort_t* __restrict__ hbf,
                                                  const ushort_t* __restrict__ dombf,
                                                  const float* __restrict__ h2,
                                                  const float* __restrict__ d2,
                                                  ushort_t* __restrict__ Kbf,
                                                  float* __restrict__ sj,
                                                  float* __restrict__ kdd) {
    __shared__ ushort_t smem[24576];         // 48 KB: As 64x128 (16K) + Bs 128x128 (32K)
    short* As = (short*)smem;                // [64][128] swizzled
    short* Bs = (short*)(smem + 8192);       // [128][128] swizzled
    const int xb = blockIdx.x;
    const int p0 = blockIdx.y * 128;
    const bool gramBlk = (xb < 2);
    const int b0 = gramBlk ? (p0 + xb * 64) : (xb - 2) * 64;
    const ushort_t* Aglob = gramBlk ? dombf : hbf;
    const int tid = threadIdx.x;
    const int wid = tid >> 6, lane = tid & 63;
    const int wm = wid >> 1, wn = wid & 1;
    const int lcol = lane & 15, quad = lane >> 4;

    f32x4 acc[2][4];
    for (int i = 0; i < 2; ++i)
        for (int n = 0; n < 4; ++n) acc[i][n] = (f32x4){0.f, 0.f, 0.f, 0.f};

    for (int kk = 0; kk < F_SZ; kk += 128) {
#pragma unroll
        for (int l = 0; l < 4; ++l) {        // A: 64 rows x 16 chunks
            int s = l * 256 + tid;
            int row = s >> 4, c = s & 15;
            int gc = c ^ (row & 15);
            gload_lds16(Aglob + (size_t)(b0 + row) * F_SZ + kk + gc * 8, &As[s * 8]);
        }
#pragma unroll
        for (int l = 0; l < 8; ++l) {        // B: 128 rows x 16 chunks
            int s = l * 256 + tid;
            int row = s >> 4, c = s & 15;
            int gc = c ^ (row & 15);
            gload_lds16(dombf + (size_t)(p0 + row) * F_SZ + kk + gc * 8, &Bs[s * 8]);
        }
        __syncthreads();
        bf16x8 ar[2][4], br[4][4];
#pragma unroll
        for (int i = 0; i < 2; ++i) {
            int r = wm * 32 + i * 16 + lcol;
#pragma unroll
            for (int ks = 0; ks < 4; ++ks)
                ar[i][ks] = *(const bf16x8*)&As[r * 128 + ((ks * 4 + quad) ^ (r & 15)) * 8];
        }
#pragma unroll
        for (int n = 0; n < 4; ++n) {
            int r = wn * 64 + n * 16 + lcol;
#pragma unroll
            for (int ks = 0; ks < 4; ++ks)
                br[n][ks] = *(const bf16x8*)&Bs[r * 128 + ((ks * 4 + quad) ^ (r & 15)) * 8];
        }
#pragma unroll
        for (int ks = 0; ks < 4; ++ks)
#pragma unroll
            for (int i = 0; i < 2; ++i)
#pragma unroll
                for (int n = 0; n < 4; ++n)
                    acc[i][n] = __builtin_amdgcn_mfma_f32_16x16x32_bf16(ar[i][ks], br[n][ks], acc[i][n], 0, 0, 0);
        __syncthreads();
    }

    float d2v[4];
#pragma unroll
    for (int n = 0; n < 4; ++n) d2v[n] = d2[p0 + wn * 64 + n * 16 + lcol];

    if (gramBlk) {
        // ---- Gram epilogue: kdd[j] from the valid 64x64 half (wn == xb) ----
        int j = blockIdx.y * 2 + xb;
        float s = 0.f;
        if (wn == xb) {
#pragma unroll
            for (int i = 0; i < 2; ++i) {
#pragma unroll
                for (int r = 0; r < 4; ++r) {
                    float d2r = d2[b0 + wm * 32 + i * 16 + quad * 4 + r];
#pragma unroll
                    for (int n = 0; n < 4; ++n) {
                        float sq = d2r + d2v[n] - 2.f * acc[i][n][r];
                        s += __expf(-2.f * sq);
                    }
                }
            }
        }
        float* red = (float*)smem;
        red[tid] = s;
        __syncthreads();
        for (int off = 128; off; off >>= 1) {
            if (tid < off) red[tid] += red[tid + off];
            __syncthreads();
        }
        if (tid == 0) kdd[j] = red[0] * (1.f / 4096.f);
        return;
    }

    // ---- normal epilogue: exp, sj reduction, stash bf16 ----
    const int jg = (p0 >> 6) + wn;
    unsigned int stash[2][4][2];
#pragma unroll
    for (int i = 0; i < 2; ++i) {
#pragma unroll
        for (int r = 0; r < 4; ++r) {
            int b = b0 + wm * 32 + i * 16 + quad * 4 + r;
            float h2v = h2[b];
            float rs = 0.f;
            ushort_t kv[4];
#pragma unroll
            for (int n = 0; n < 4; ++n) {
                float sq = h2v + d2v[n] - 2.f * acc[i][n][r];
                float kvf = __expf(-2.f * sq);
                kv[n] = f2bf(kvf);
                rs += kvf;
            }
            stash[i][r][0] = (unsigned int)kv[0] | ((unsigned int)kv[1] << 16);
            stash[i][r][1] = (unsigned int)kv[2] | ((unsigned int)kv[3] << 16);
            rs += __shfl_xor(rs, 1);
            rs += __shfl_xor(rs, 2);
            rs += __shfl_xor(rs, 4);
            rs += __shfl_xor(rs, 8);
            if (lcol == 0) sj[(size_t)b * J_SZ + jg] = rs * (1.f / M_SZ);
        }
    }

    // ---- repack: C-layout -> LDSC[64][132] -> coalesced 8B stores ----
    ushort_t* LDSC = smem;                   // 16.9 KB <= 48 KB
#pragma unroll
    for (int i = 0; i < 2; ++i) {
#pragma unroll
        for (int r = 0; r < 4; ++r) {
            int row = wm * 32 + i * 16 + quad * 4 + r;
#pragma unroll
            for (int n = 0; n < 4; ++n) {
                ushort_t v = (ushort_t)(stash[i][r][n >> 1] >> ((n & 1) * 16));
                LDSC[row * 132 + wn * 64 + n * 16 + lcol] = v;
            }
        }
    }
    __syncthreads();
#pragma unroll
    for (int l = 0; l < 8; ++l) {
        int u = l * 256 + tid;               // 2048 ushort4 units
        int row = u >> 5, segc = (u & 31) * 4;
        ushort4 v = *(const ushort4*)&LDSC[row * 132 + segc];
        *(ushort4*)&Kbf[(size_t)(b0 + row) * P_SZ + p0 + segc] = v;
    }
}

// ---------------------------------------------------------------------------
// gemm2_mfma: out = sum_j prob_j*(K_j . W_j + bias_j). 64x64 tile, BK=128
// = TWO domains per stage (8 stages), prob folded per domain.
// XOR-swizzled LDS (16 chunks/row). 512 blocks (2/CU, ~40 KB LDS).
// ---------------------------------------------------------------------------
__global__ __launch_bounds__(256) void gemm2_mfma(const ushort_t* __restrict__ Ks,
                                                  const ushort_t* __restrict__ Wt,
                                                  const float* __restrict__ sj,
                                                  const float* __restrict__ kdd,
                                                  const float* __restrict__ bias,
                                                  float* __restrict__ out) {
    __shared__ short As[64 * 128];           // 16 KB swizzled
    __shared__ short Bs[64 * 128];           // 16 KB swizzled
    __shared__ float probS[64 * 17];         // 4.25 KB
    __shared__ float biasS[16 * 64];         // 4 KB
    __shared__ float kddS[J_SZ];
    const int b0 = blockIdx.x * 64;
    const int u0 = blockIdx.y * 64;
    const int tid = threadIdx.x;
    const int wid = tid >> 6, lane = tid & 63;
    const int wm = wid >> 1, wn = wid & 1;
    const int lcol = lane & 15, quad = lane >> 4;

    if (tid < J_SZ) kddS[tid] = kdd[tid];
    {
        int rowj = tid >> 4, c4 = (tid & 15) << 2;
        *(float4*)&biasS[rowj * 64 + c4] = *(const float4*)&bias[(size_t)rowj * U_SZ + u0 + c4];
    }
    __syncthreads();
    if (tid < 64) {
        int b = b0 + tid;
        float lg[J_SZ], mx = -1e30f;
#pragma unroll
        for (int j = 0; j < J_SZ; ++j) {
            lg[j] = 2.f * sj[(size_t)b * J_SZ + j] - kddS[j] - 1.f;
            mx = fmaxf(mx, lg[j]);
        }
        float ssum = 0.f;
#pragma unroll
        for (int j = 0; j < J_SZ; ++j) { lg[j] = __expf(lg[j] - mx); ssum += lg[j]; }
        float inv = 1.f / ssum;
#pragma unroll
        for (int j = 0; j < J_SZ; ++j) probS[tid * 17 + j] = lg[j] * inv;
    }
    __syncthreads();

    f32x4 acc_tot[2][2];
    for (int i = 0; i < 2; ++i)
        for (int n = 0; n < 2; ++n) acc_tot[i][n] = (f32x4){0.f, 0.f, 0.f, 0.f};

    for (int jb = 0; jb < 8; ++jb) {
        int kk = jb * 128;                   // covers domains 2*jb, 2*jb+1
#pragma unroll
        for (int l = 0; l < 4; ++l) {        // A & B: 64 rows x 16 chunks each
            int s = l * 256 + tid;
            int row = s >> 4, c = s & 15;
            int gc = c ^ (row & 15);
            gload_lds16(Ks + (size_t)(b0 + row) * P_SZ + kk + gc * 8, &As[s * 8]);
            gload_lds16(Wt + (size_t)(u0 + row) * P_SZ + kk + gc * 8, &Bs[s * 8]);
        }
        __syncthreads();
        bf16x8 ar[2][4], br[2][4];
#pragma unroll
        for (int i = 0; i < 2; ++i) {
            int r = wm * 32 + i * 16 + lcol;
#pragma unroll
            for (int ks = 0; ks < 4; ++ks)
                ar[i][ks] = *(const bf16x8*)&As[r * 128 + ((ks * 4 + quad) ^ (r & 15)) * 8];
        }
#pragma unroll
        for (int n = 0; n < 2; ++n) {
            int r = wn * 32 + n * 16 + lcol;
#pragma unroll
            for (int ks = 0; ks < 4; ++ks)
                br[n][ks] = *(const bf16x8*)&Bs[r * 128 + ((ks * 4 + quad) ^ (r & 15)) * 8];
        }
        // domain 0 of this stage: ks 0,1 ; domain 1: ks 2,3
        f32x4 ac0[2][2], ac1[2][2];
#pragma unroll
        for (int i = 0; i < 2; ++i)
#pragma unroll
            for (int n = 0; n < 2; ++n) {
                ac0[i][n] = (f32x4){0.f, 0.f, 0.f, 0.f};
                ac1[i][n] = (f32x4){0.f, 0.f, 0.f, 0.f};
            }
#pragma unroll
        for (int ks = 0; ks < 2; ++ks)
#pragma unroll
            for (int i = 0; i < 2; ++i)
#pragma unroll
                for (int n = 0; n < 2; ++n)
                    ac0[i][n] = __builtin_amdgcn_mfma_f32_16x16x32_bf16(ar[i][ks], br[n][ks], ac0[i][n], 0, 0, 0);
#pragma unroll
        for (int ks = 2; ks < 4; ++ks)
#pragma unroll
            for (int i = 0; i < 2; ++i)
#pragma unroll
                for (int n = 0; n < 2; ++n)
                    ac1[i][n] = __builtin_amdgcn_mfma_f32_16x16x32_bf16(ar[i][ks], br[n][ks], ac1[i][n], 0, 0, 0);
        __syncthreads();
        // fold both domains' partials with their probabilities
#pragma unroll
        for (int i = 0; i < 2; ++i) {
#pragma unroll
            for (int r = 0; r < 4; ++r) {
                int row = wm * 32 + i * 16 + quad * 4 + r;
                float pf0 = probS[row * 17 + 2 * jb];
                float pf1 = probS[row * 17 + 2 * jb + 1];
#pragma unroll
                for (int n = 0; n < 2; ++n)
                    acc_tot[i][n][r] += pf0 * ac0[i][n][r] + pf1 * ac1[i][n][r];
            }
        }
    }

    // ---- epilogue: + sum_j prob*bias ----
    float bv[2][J_SZ];
#pragma unroll
    for (int n = 0; n < 2; ++n) {
        int col = wn * 32 + n * 16 + lcol;
#pragma unroll
        for (int j = 0; j < J_SZ; ++j) bv[n][j] = biasS[j * 64 + col];
    }
#pragma unroll
    for (int i = 0; i < 2; ++i) {
#pragma unroll
        for (int r = 0; r < 4; ++r) {
            int row = wm * 32 + i * 16 + quad * 4 + r;
            int b = b0 + row;
#pragma unroll
            for (int n = 0; n < 2; ++n) {
                float a = acc_tot[i][n][r];
#pragma unroll
                for (int j = 0; j < J_SZ; ++j) a += probS[row * 17 + j] * bv[n][j];
                out[(size_t)b * U_SZ + u0 + wn * 32 + n * 16 + lcol] = a;
            }
        }
    }
}

// ---------------------------------------------------------------------------
extern "C" void kernel_launch(void* const* d_in, const int* in_sizes, int n_in,
                              void* d_out, int out_size, void* d_ws, size_t ws_size,
                              hipStream_t stream) {
    const float* h    = (const float*)d_in[0];   // [B,F]
    const float* dom  = (const float*)d_in[1];   // [J,M,F]
    const float* W    = (const float*)d_in[2];   // [J,M,U]
    const float* bias = (const float*)d_in[3];   // [J,U]
    float* out = (float*)d_out;                  // [B,U]

    char* ws = (char*)d_ws;
    ushort_t* hbf   = (ushort_t*)ws;  ws += (size_t)B_SZ * F_SZ * 2;   // 4 MB
    ushort_t* dombf = (ushort_t*)ws;  ws += (size_t)P_SZ * F_SZ * 2;   // 1 MB
    ushort_t* Wt    = (ushort_t*)ws;  ws += (size_t)U_SZ * P_SZ * 2;   // 1 MB
    ushort_t* Kbf   = (ushort_t*)ws;  ws += (size_t)B_SZ * P_SZ * 2;   // 8 MB
    float* h2  = (float*)ws;  ws += B_SZ * 4;
    float* d2  = (float*)ws;  ws += P_SZ * 4;
    float* kdd = (float*)ws;  ws += 64;
    float* sj  = (float*)ws;  ws += (size_t)B_SZ * J_SZ * 4;

    prep_kernel<<<1408, 256, 0, stream>>>(h, dom, W, hbf, dombf, Wt, h2, d2);
    gemm1_mfma<<<dim3(66, P_SZ / 128), 256, 0, stream>>>(hbf, dombf, h2, d2, Kbf, sj, kdd);
    gemm2_mfma<<<dim3(B_SZ / 64, U_SZ / 64), 256, 0, stream>>>(Kbf, Wt, sj, kdd, bias, out);
}

// Round 10
// 93.039 us; speedup vs baseline: 1.2230x; 1.0228x over previous
//
#include <hip/hip_runtime.h>
#include <math.h>

typedef unsigned short ushort_t;
typedef __attribute__((ext_vector_type(8))) short bf16x8;
typedef __attribute__((ext_vector_type(4))) float f32x4;

#define B_SZ 4096
#define F_SZ 512
#define J_SZ 16
#define M_SZ 64
#define U_SZ 512
#define P_SZ 1024

__device__ __forceinline__ ushort_t f2bf(float f) {
    union { float f; unsigned int u; } v; v.f = f;
    unsigned int r = (v.u + 0x7FFFu + ((v.u >> 16) & 1u)) >> 16;
    return (ushort_t)r;
}

// async global->LDS, 16 bytes per lane (wave-uniform LDS base + lane*16)
__device__ __forceinline__ void gload_lds16(const void* g, void* l) {
    __builtin_amdgcn_global_load_lds(
        (const __attribute__((address_space(1))) unsigned int*)g,
        (__attribute__((address_space(3))) unsigned int*)l, 16, 0, 0);
}

// ---------------------------------------------------------------------------
// prep: block-role fused preprocessing (1408 blocks) — conversions only.
//   [0,1024):    h fp32->bf16 + h2            (4 rows/block)
//   [1024,1280): dom fp32->bf16 + d2          (4 rows/block)
//   [1280,1408): W [p][u] -> Wt [u][p] bf16   (64x64 LDS transpose)
// ---------------------------------------------------------------------------
__global__ __launch_bounds__(256) void prep_kernel(const float* __restrict__ h,
                                                   const float* __restrict__ dom,
                                                   const float* __restrict__ W,
                                                   ushort_t* __restrict__ hbf,
                                                   ushort_t* __restrict__ dombf,
                                                   ushort_t* __restrict__ Wt,
                                                   float* __restrict__ h2,
                                                   float* __restrict__ d2) {
    const int bid = blockIdx.x;
    const int tid = threadIdx.x;

    if (bid < 1024) {                       // ---- cvt_h ----
        int b = bid * 4 + (tid >> 6);
        int lane = tid & 63;
        const float4* row = (const float4*)(h + (size_t)b * F_SZ);
        ushort4* orow = (ushort4*)(hbf + (size_t)b * F_SZ);
        float s = 0.f;
        for (int i = lane; i < F_SZ / 4; i += 64) {
            float4 v = row[i];
            s += v.x * v.x + v.y * v.y + v.z * v.z + v.w * v.w;
            ushort4 o; o.x = f2bf(v.x); o.y = f2bf(v.y); o.z = f2bf(v.z); o.w = f2bf(v.w);
            orow[i] = o;
        }
        for (int off = 32; off; off >>= 1) s += __shfl_down(s, off);
        if (lane == 0) h2[b] = s;
    } else if (bid < 1280) {                // ---- cvt_dom ----
        int p = (bid - 1024) * 4 + (tid >> 6);
        int lane = tid & 63;
        const float4* row = (const float4*)(dom + (size_t)p * F_SZ);
        ushort4* orow = (ushort4*)(dombf + (size_t)p * F_SZ);
        float s = 0.f;
        for (int i = lane; i < F_SZ / 4; i += 64) {
            float4 v = row[i];
            s += v.x * v.x + v.y * v.y + v.z * v.z + v.w * v.w;
            ushort4 o; o.x = f2bf(v.x); o.y = f2bf(v.y); o.z = f2bf(v.z); o.w = f2bf(v.w);
            orow[i] = o;
        }
        for (int off = 32; off; off >>= 1) s += __shfl_down(s, off);
        if (lane == 0) d2[p] = s;
    } else {                                // ---- cvt_w (transpose) ----
        int idx = bid - 1280;
        int pt = (idx >> 3) * 64, ut = (idx & 7) * 64;
        __shared__ ushort_t T[64][72];
        for (int l = 0; l < 4; ++l) {
            int s = l * 256 + tid;
            int r = s >> 4, c4 = (s & 15) << 2;
            float4 v = *(const float4*)&W[(size_t)(pt + r) * U_SZ + ut + c4];
            T[c4 + 0][r] = f2bf(v.x); T[c4 + 1][r] = f2bf(v.y);
            T[c4 + 2][r] = f2bf(v.z); T[c4 + 3][r] = f2bf(v.w);
        }
        __syncthreads();
        for (int l = 0; l < 4; ++l) {
            int s = l * 256 + tid;
            int r2 = s >> 4, c4 = (s & 15) << 2;
            ushort4 o; o.x = T[r2][c4 + 0]; o.y = T[r2][c4 + 1];
            o.z = T[r2][c4 + 2]; o.w = T[r2][c4 + 3];
            *(ushort4*)&Wt[(size_t)(ut + r2) * P_SZ + pt + c4] = o;
        }
    }
}

// ---------------------------------------------------------------------------
// gemm1_mfma: 64x128 tile, BK=128 (4 iters), XOR-swizzled LDS. Grid (72, 8)
// — x padded 66->72 so the 8 y-readers of each hbf A-tile share one XCD
// (bids spaced 72, 72%8==0 -> same XCD L2; per-XCD A working set 576 KB).
//   x in {0,1}: Gram blocks (dispatched FIRST): A = dombf rows of j=y*2+x;
//               epilogue reduces kdd[j] = mean exp(-2*(d2m+d2n-2*G)).
//   x in [2,66): normal: A = hbf rows (x-2)*64; K=exp(-2*(h2+d2-2c)) -> sj,
//               Kbf via LDS repack.
//   x >= 66:   no-op pad blocks.
// ---------------------------------------------------------------------------
__global__ __launch_bounds__(256) void gemm1_mfma(const ushort_t* __restrict__ hbf,
                                                  const ushort_t* __restrict__ dombf,
                                                  const float* __restrict__ h2,
                                                  const float* __restrict__ d2,
                                                  ushort_t* __restrict__ Kbf,
                                                  float* __restrict__ sj,
                                                  float* __restrict__ kdd) {
    const int xb = blockIdx.x;
    if (xb >= 66) return;                    // XCD-alignment pad
    __shared__ ushort_t smem[24576];         // 48 KB: As 64x128 (16K) + Bs 128x128 (32K)
    short* As = (short*)smem;                // [64][128] swizzled
    short* Bs = (short*)(smem + 8192);       // [128][128] swizzled
    const int p0 = blockIdx.y * 128;
    const bool gramBlk = (xb < 2);
    const int b0 = gramBlk ? (p0 + xb * 64) : (xb - 2) * 64;
    const ushort_t* Aglob = gramBlk ? dombf : hbf;
    const int tid = threadIdx.x;
    const int wid = tid >> 6, lane = tid & 63;
    const int wm = wid >> 1, wn = wid & 1;
    const int lcol = lane & 15, quad = lane >> 4;

    f32x4 acc[2][4];
    for (int i = 0; i < 2; ++i)
        for (int n = 0; n < 4; ++n) acc[i][n] = (f32x4){0.f, 0.f, 0.f, 0.f};

    for (int kk = 0; kk < F_SZ; kk += 128) {
#pragma unroll
        for (int l = 0; l < 4; ++l) {        // A: 64 rows x 16 chunks
            int s = l * 256 + tid;
            int row = s >> 4, c = s & 15;
            int gc = c ^ (row & 15);
            gload_lds16(Aglob + (size_t)(b0 + row) * F_SZ + kk + gc * 8, &As[s * 8]);
        }
#pragma unroll
        for (int l = 0; l < 8; ++l) {        // B: 128 rows x 16 chunks
            int s = l * 256 + tid;
            int row = s >> 4, c = s & 15;
            int gc = c ^ (row & 15);
            gload_lds16(dombf + (size_t)(p0 + row) * F_SZ + kk + gc * 8, &Bs[s * 8]);
        }
        __syncthreads();
        bf16x8 ar[2][4], br[4][4];
#pragma unroll
        for (int i = 0; i < 2; ++i) {
            int r = wm * 32 + i * 16 + lcol;
#pragma unroll
            for (int ks = 0; ks < 4; ++ks)
                ar[i][ks] = *(const bf16x8*)&As[r * 128 + ((ks * 4 + quad) ^ (r & 15)) * 8];
        }
#pragma unroll
        for (int n = 0; n < 4; ++n) {
            int r = wn * 64 + n * 16 + lcol;
#pragma unroll
            for (int ks = 0; ks < 4; ++ks)
                br[n][ks] = *(const bf16x8*)&Bs[r * 128 + ((ks * 4 + quad) ^ (r & 15)) * 8];
        }
#pragma unroll
        for (int ks = 0; ks < 4; ++ks)
#pragma unroll
            for (int i = 0; i < 2; ++i)
#pragma unroll
                for (int n = 0; n < 4; ++n)
                    acc[i][n] = __builtin_amdgcn_mfma_f32_16x16x32_bf16(ar[i][ks], br[n][ks], acc[i][n], 0, 0, 0);
        __syncthreads();
    }

    float d2v[4];
#pragma unroll
    for (int n = 0; n < 4; ++n) d2v[n] = d2[p0 + wn * 64 + n * 16 + lcol];

    if (gramBlk) {
        // ---- Gram epilogue: kdd[j] from the valid 64x64 half (wn == xb) ----
        int j = blockIdx.y * 2 + xb;
        float s = 0.f;
        if (wn == xb) {
#pragma unroll
            for (int i = 0; i < 2; ++i) {
#pragma unroll
                for (int r = 0; r < 4; ++r) {
                    float d2r = d2[b0 + wm * 32 + i * 16 + quad * 4 + r];
#pragma unroll
                    for (int n = 0; n < 4; ++n) {
                        float sq = d2r + d2v[n] - 2.f * acc[i][n][r];
                        s += __expf(-2.f * sq);
                    }
                }
            }
        }
        float* red = (float*)smem;
        red[tid] = s;
        __syncthreads();
        for (int off = 128; off; off >>= 1) {
            if (tid < off) red[tid] += red[tid + off];
            __syncthreads();
        }
        if (tid == 0) kdd[j] = red[0] * (1.f / 4096.f);
        return;
    }

    // ---- normal epilogue: exp, sj reduction, stash bf16 ----
    const int jg = (p0 >> 6) + wn;
    unsigned int stash[2][4][2];
#pragma unroll
    for (int i = 0; i < 2; ++i) {
#pragma unroll
        for (int r = 0; r < 4; ++r) {
            int b = b0 + wm * 32 + i * 16 + quad * 4 + r;
            float h2v = h2[b];
            float rs = 0.f;
            ushort_t kv[4];
#pragma unroll
            for (int n = 0; n < 4; ++n) {
                float sq = h2v + d2v[n] - 2.f * acc[i][n][r];
                float kvf = __expf(-2.f * sq);
                kv[n] = f2bf(kvf);
                rs += kvf;
            }
            stash[i][r][0] = (unsigned int)kv[0] | ((unsigned int)kv[1] << 16);
            stash[i][r][1] = (unsigned int)kv[2] | ((unsigned int)kv[3] << 16);
            rs += __shfl_xor(rs, 1);
            rs += __shfl_xor(rs, 2);
            rs += __shfl_xor(rs, 4);
            rs += __shfl_xor(rs, 8);
            if (lcol == 0) sj[(size_t)b * J_SZ + jg] = rs * (1.f / M_SZ);
        }
    }

    // ---- repack: C-layout -> LDSC[64][132] -> coalesced 8B stores ----
    ushort_t* LDSC = smem;                   // 16.9 KB <= 48 KB
#pragma unroll
    for (int i = 0; i < 2; ++i) {
#pragma unroll
        for (int r = 0; r < 4; ++r) {
            int row = wm * 32 + i * 16 + quad * 4 + r;
#pragma unroll
            for (int n = 0; n < 4; ++n) {
                ushort_t v = (ushort_t)(stash[i][r][n >> 1] >> ((n & 1) * 16));
                LDSC[row * 132 + wn * 64 + n * 16 + lcol] = v;
            }
        }
    }
    __syncthreads();
#pragma unroll
    for (int l = 0; l < 8; ++l) {
        int u = l * 256 + tid;               // 2048 ushort4 units
        int row = u >> 5, segc = (u & 31) * 4;
        ushort4 v = *(const ushort4*)&LDSC[row * 132 + segc];
        *(ushort4*)&Kbf[(size_t)(b0 + row) * P_SZ + p0 + segc] = v;
    }
}

// ---------------------------------------------------------------------------
// gemm2_mfma: out = sum_j prob_j*(K_j . W_j + bias_j). 64x64 tile, BK=256
// = FOUR domains per stage (4 stages, 8 barriers), prob folded per domain
// via per-domain accumulators. XOR-swizzled LDS (32 chunks/row).
// 512 blocks (2/CU, ~72 KB LDS). Softmax from sj+kdd in prologue.
// ---------------------------------------------------------------------------
__global__ __launch_bounds__(256) void gemm2_mfma(const ushort_t* __restrict__ Ks,
                                                  const ushort_t* __restrict__ Wt,
                                                  const float* __restrict__ sj,
                                                  const float* __restrict__ kdd,
                                                  const float* __restrict__ bias,
                                                  float* __restrict__ out) {
    __shared__ short As[64 * 256];           // 32 KB swizzled
    __shared__ short Bs[64 * 256];           // 32 KB swizzled
    __shared__ float probS[64 * 17];         // 4.25 KB
    __shared__ float biasS[16 * 64];         // 4 KB
    __shared__ float kddS[J_SZ];
    const int b0 = blockIdx.x * 64;
    const int u0 = blockIdx.y * 64;
    const int tid = threadIdx.x;
    const int wid = tid >> 6, lane = tid & 63;
    const int wm = wid >> 1, wn = wid & 1;
    const int lcol = lane & 15, quad = lane >> 4;

    if (tid < J_SZ) kddS[tid] = kdd[tid];
    {
        int rowj = tid >> 4, c4 = (tid & 15) << 2;
        *(float4*)&biasS[rowj * 64 + c4] = *(const float4*)&bias[(size_t)rowj * U_SZ + u0 + c4];
    }
    __syncthreads();
    if (tid < 64) {
        int b = b0 + tid;
        float lg[J_SZ], mx = -1e30f;
#pragma unroll
        for (int j = 0; j < J_SZ; ++j) {
            lg[j] = 2.f * sj[(size_t)b * J_SZ + j] - kddS[j] - 1.f;
            mx = fmaxf(mx, lg[j]);
        }
        float ssum = 0.f;
#pragma unroll
        for (int j = 0; j < J_SZ; ++j) { lg[j] = __expf(lg[j] - mx); ssum += lg[j]; }
        float inv = 1.f / ssum;
#pragma unroll
        for (int j = 0; j < J_SZ; ++j) probS[tid * 17 + j] = lg[j] * inv;
    }
    __syncthreads();

    f32x4 acc_tot[2][2];
    for (int i = 0; i < 2; ++i)
        for (int n = 0; n < 2; ++n) acc_tot[i][n] = (f32x4){0.f, 0.f, 0.f, 0.f};

    for (int jb = 0; jb < 4; ++jb) {
        int kk = jb * 256;                   // covers domains 4*jb .. 4*jb+3
#pragma unroll
        for (int l = 0; l < 8; ++l) {        // A & B: 64 rows x 32 chunks each
            int s = l * 256 + tid;
            int row = s >> 5, c = s & 31;
            int gc = c ^ (row & 31);
            gload_lds16(Ks + (size_t)(b0 + row) * P_SZ + kk + gc * 8, &As[s * 8]);
            gload_lds16(Wt + (size_t)(u0 + row) * P_SZ + kk + gc * 8, &Bs[s * 8]);
        }
        __syncthreads();
        // per-domain accumulators; domain d = ks>>1 (each domain = 2 ks slices)
        f32x4 ac[4][2][2];
#pragma unroll
        for (int d = 0; d < 4; ++d)
#pragma unroll
            for (int i = 0; i < 2; ++i)
#pragma unroll
                for (int n = 0; n < 2; ++n) ac[d][i][n] = (f32x4){0.f, 0.f, 0.f, 0.f};
#pragma unroll
        for (int ks = 0; ks < 8; ++ks) {
            const int d = ks >> 1;
            bf16x8 ar[2], br[2];
#pragma unroll
            for (int i = 0; i < 2; ++i) {
                int r = wm * 32 + i * 16 + lcol;
                ar[i] = *(const bf16x8*)&As[r * 256 + ((ks * 4 + quad) ^ (r & 31)) * 8];
            }
#pragma unroll
            for (int n = 0; n < 2; ++n) {
                int r = wn * 32 + n * 16 + lcol;
                br[n] = *(const bf16x8*)&Bs[r * 256 + ((ks * 4 + quad) ^ (r & 31)) * 8];
            }
#pragma unroll
            for (int i = 0; i < 2; ++i)
#pragma unroll
                for (int n = 0; n < 2; ++n)
                    ac[d][i][n] = __builtin_amdgcn_mfma_f32_16x16x32_bf16(ar[i], br[n], ac[d][i][n], 0, 0, 0);
        }
        __syncthreads();
        // fold the four domains' partials with their probabilities
#pragma unroll
        for (int i = 0; i < 2; ++i) {
#pragma unroll
            for (int r = 0; r < 4; ++r) {
                int row = wm * 32 + i * 16 + quad * 4 + r;
#pragma unroll
                for (int d = 0; d < 4; ++d) {
                    float pf = probS[row * 17 + 4 * jb + d];
#pragma unroll
                    for (int n = 0; n < 2; ++n)
                        acc_tot[i][n][r] += pf * ac[d][i][n][r];
                }
            }
        }
    }

    // ---- epilogue: + sum_j prob*bias ----
    float bv[2][J_SZ];
#pragma unroll
    for (int n = 0; n < 2; ++n) {
        int col = wn * 32 + n * 16 + lcol;
#pragma unroll
        for (int j = 0; j < J_SZ; ++j) bv[n][j] = biasS[j * 64 + col];
    }
#pragma unroll
    for (int i = 0; i < 2; ++i) {
#pragma unroll
        for (int r = 0; r < 4; ++r) {
            int row = wm * 32 + i * 16 + quad * 4 + r;
            int b = b0 + row;
#pragma unroll
            for (int n = 0; n < 2; ++n) {
                float a = acc_tot[i][n][r];
#pragma unroll
                for (int j = 0; j < J_SZ; ++j) a += probS[row * 17 + j] * bv[n][j];
                out[(size_t)b * U_SZ + u0 + wn * 32 + n * 16 + lcol] = a;
            }
        }
    }
}

// ---------------------------------------------------------------------------
extern "C" void kernel_launch(void* const* d_in, const int* in_sizes, int n_in,
                              void* d_out, int out_size, void* d_ws, size_t ws_size,
                              hipStream_t stream) {
    const float* h    = (const float*)d_in[0];   // [B,F]
    const float* dom  = (const float*)d_in[1];   // [J,M,F]
    const float* W    = (const float*)d_in[2];   // [J,M,U]
    const float* bias = (const float*)d_in[3];   // [J,U]
    float* out = (float*)d_out;                  // [B,U]

    char* ws = (char*)d_ws;
    ushort_t* hbf   = (ushort_t*)ws;  ws += (size_t)B_SZ * F_SZ * 2;   // 4 MB
    ushort_t* dombf = (ushort_t*)ws;  ws += (size_t)P_SZ * F_SZ * 2;   // 1 MB
    ushort_t* Wt    = (ushort_t*)ws;  ws += (size_t)U_SZ * P_SZ * 2;   // 1 MB
    ushort_t* Kbf   = (ushort_t*)ws;  ws += (size_t)B_SZ * P_SZ * 2;   // 8 MB
    float* h2  = (float*)ws;  ws += B_SZ * 4;
    float* d2  = (float*)ws;  ws += P_SZ * 4;
    float* kdd = (float*)ws;  ws += 64;
    float* sj  = (float*)ws;  ws += (size_t)B_SZ * J_SZ * 4;

    prep_kernel<<<1408, 256, 0, stream>>>(h, dom, W, hbf, dombf, Wt, h2, d2);
    gemm1_mfma<<<dim3(72, P_SZ / 128), 256, 0, stream>>>(hbf, dombf, h2, d2, Kbf, sj, kdd);
    gemm2_mfma<<<dim3(B_SZ / 64, U_SZ / 64), 256, 0, stream>>>(Kbf, Wt, sj, kdd, bias, out);
}